// Round 3
// baseline (4982.069 us; speedup 1.0000x reference)
//
#include <hip/hip_runtime.h>
#include <math.h>

// ---------------------------------------------------------------------------
// Batched Levenberg-Marquardt, Huber IRLS, B=32, M=307200, N=4, 30 steps.
//
// Fusion: cost(theta_k) and H,G(theta_k) computed in ONE pass (the reference
// always accepts the step).  31 data passes total.
//
// R3 change: occupancy fix.  R1 vs R2 showed per-wave ILP is not the lever
// (same 2.36 TB/s effective at 2 vs 18 loads in flight); the kernel is
// latency-bound on wave count.  Now: 80 blocks/batch (2560 blocks, 10/CU),
// __launch_bounds__(256,8) to cap VGPR at 64 -> 8 waves/SIMD static, unroll 3
// (fits the 64-VGPR budget).  80*256*3*5 == 307200 exactly, no tail.
//
// ws layout (floats):
//   [0,128)    theta (32x4) | [128,256) eval_theta | [256,288) lambda
//   [288,320)  cost  | [320,352) stop | [352, 352+32*80*16) partials
// ---------------------------------------------------------------------------

#define B_      32
#define M_      307200
#define NSTEPS  30
#define BPB     80                    // blocks per batch
#define THREADS 256
#define TPBATCH (BPB * THREADS)       // 20480 threads per batch
#define UNROLL  3
#define OUTER   5                     // OUTER*UNROLL*TPBATCH == M_

#define WS_THETA 0
#define WS_EVAL  128
#define WS_LAMB  256
#define WS_COST  288
#define WS_STOP  320
#define WS_PART  352

__global__ void lm_init(float* __restrict__ ws, const float* __restrict__ theta0) {
    int i = threadIdx.x;
    if (i < 128) {
        float t = theta0[i];
        ws[WS_THETA + i] = t;
        ws[WS_EVAL + i]  = t;
    }
    if (i < 32) {
        ws[WS_LAMB + i] = 0.1f;
        ws[WS_COST + i] = 0.0f;
        ((int*)(ws + WS_STOP))[i] = 0;
    }
}

__global__ __launch_bounds__(THREADS, 8) void lm_pass(
        const float* __restrict__ J, const float* __restrict__ bvec,
        const float* __restrict__ conf, float* __restrict__ ws) {
    const int batch = blockIdx.x & 31;
    const int chunk = blockIdx.x >> 5;

    const int* stopf = (const int*)(ws + WS_STOP);
    if (stopf[batch]) return;   // frozen batch: results would be discarded

    const float* th = ws + WS_EVAL + batch * 4;
    const float t0 = th[0], t1 = th[1], t2 = th[2], t3 = th[3];

    const float4* __restrict__ Jb = (const float4*)(J + (size_t)batch * M_ * 4);
    const float*  __restrict__ bb = bvec + (size_t)batch * M_;
    const float*  __restrict__ cb = conf + (size_t)batch * M_;

    float c_acc = 0.f;
    float g0 = 0.f, g1 = 0.f, g2 = 0.f, g3 = 0.f;
    float h00 = 0.f, h01 = 0.f, h02 = 0.f, h03 = 0.f;
    float h11 = 0.f, h12 = 0.f, h13 = 0.f;
    float h22 = 0.f, h23 = 0.f, h33 = 0.f;

    const int m0 = chunk * THREADS + (int)threadIdx.x;    // [0, TPBATCH)

    for (int outer = 0; outer < OUTER; ++outer) {
        const int base = outer * (UNROLL * TPBATCH) + m0;
        float4 jv[UNROLL];
        float  bv[UNROLL];
        float  cf[UNROLL];
        #pragma unroll
        for (int k = 0; k < UNROLL; ++k) {
            const int m = base + k * TPBATCH;
            jv[k] = Jb[m];
            bv[k] = bb[m];
            cf[k] = cb[m];
        }
        #pragma unroll
        for (int k = 0; k < UNROLL; ++k) {
            float pred = jv[k].x * t0 + jv[k].y * t1 + jv[k].z * t2 + jv[k].w * t3;
            float r = bv[k] - pred;
            // scaled huber, a = 0.01 -> a^2 = 1e-4, x = r^2 / a^2
            float x  = r * r * 1.0e4f;
            float sx = sqrtf(x + 1e-8f);
            float isx = fmaxf(1.1920929e-7f, 1.0f / sx);
            bool small = (x <= 1.0f);
            float loss = small ? x : (2.0f * sx - 1.0f);
            float d1   = small ? 1.0f : isx;
            c_acc += loss * 1.0e-4f * cf[k];
            float w  = d1 * cf[k];
            float wr = w * r;
            g0 += wr * jv[k].x; g1 += wr * jv[k].y;
            g2 += wr * jv[k].z; g3 += wr * jv[k].w;
            float wx = w * jv[k].x, wy = w * jv[k].y, wz = w * jv[k].z;
            h00 += wx * jv[k].x; h01 += wx * jv[k].y;
            h02 += wx * jv[k].z; h03 += wx * jv[k].w;
            h11 += wy * jv[k].y; h12 += wy * jv[k].z; h13 += wy * jv[k].w;
            h22 += wz * jv[k].z; h23 += wz * jv[k].w;
            h33 += (w * jv[k].w) * jv[k].w;
        }
    }

    float acc[15] = {c_acc, g0, g1, g2, g3,
                     h00, h01, h02, h03, h11, h12, h13, h22, h23, h33};
    #pragma unroll
    for (int v = 0; v < 15; ++v) {
        float s = acc[v];
        #pragma unroll
        for (int off = 32; off > 0; off >>= 1)
            s += __shfl_down(s, off, 64);
        acc[v] = s;
    }

    __shared__ float red[4][15];
    const int lane = threadIdx.x & 63;
    const int wave = threadIdx.x >> 6;
    if (lane == 0) {
        #pragma unroll
        for (int v = 0; v < 15; ++v) red[wave][v] = acc[v];
    }
    __syncthreads();
    if (threadIdx.x < 15) {
        int v = threadIdx.x;
        float s = red[0][v] + red[1][v] + red[2][v] + red[3][v];
        ws[WS_PART + (batch * BPB + chunk) * 16 + v] = s;
    }
}

// Cross-block reduce + state update + damped 4x4 Cholesky solve.
__global__ __launch_bounds__(64) void lm_solve(
        float* __restrict__ ws, float* __restrict__ out, int j) {
    const int batch = blockIdx.x;
    const int tid = threadIdx.x;
    float* theta = ws + WS_THETA + batch * 4;
    float* evalt = ws + WS_EVAL + batch * 4;
    float* lambp = ws + WS_LAMB + batch;
    float* costp = ws + WS_COST + batch;
    int*   stopp = (int*)(ws + WS_STOP) + batch;
    const float* part = ws + WS_PART + batch * BPB * 16;

    __shared__ float vals[15];
    const bool stopped = (*stopp != 0);   // block-uniform

    if (!stopped) {
        if (tid < 15) {
            float s = 0.f;
            #pragma unroll 8
            for (int k = 0; k < BPB; ++k) s += part[k * 16 + tid];
            vals[tid] = s;
        }
        __syncthreads();
        if (tid == 0) {
            float new_cost = vals[0];
            float l = *lambp;
            bool stop_now = false;
            if (j == 0) {
                *costp = new_cost;           // cost0; theta/eval already theta0
            } else {
                float prev = *costp;
                float nl = l * (new_cost > prev ? 10.0f : 0.1f);
                nl = fminf(fmaxf(nl, 1e-6f), 100.0f);
                stop_now = fabsf(new_cost - prev) <= (1e-8f + 1e-8f * fabsf(prev));
                theta[0] = evalt[0]; theta[1] = evalt[1];
                theta[2] = evalt[2]; theta[3] = evalt[3];
                *costp = new_cost;
                *lambp = nl;
                l = nl;
                if (stop_now) *stopp = 1;
            }
            if (!stop_now && j < NSTEPS) {
                float g0 = vals[1], g1 = vals[2], g2 = vals[3], g3 = vals[4];
                float a00 = vals[5],  a01 = vals[6],  a02 = vals[7], a03 = vals[8];
                float a11 = vals[9],  a12 = vals[10], a13 = vals[11];
                float a22 = vals[12], a23 = vals[13], a33 = vals[14];
                // LM damping: H[i][i] += max(lambda * H[i][i], 1e-6)
                a00 += fmaxf(l * a00, 1e-6f);
                a11 += fmaxf(l * a11, 1e-6f);
                a22 += fmaxf(l * a22, 1e-6f);
                a33 += fmaxf(l * a33, 1e-6f);
                // Cholesky
                float L00 = sqrtf(a00);
                float L10 = a01 / L00, L20 = a02 / L00, L30 = a03 / L00;
                float L11 = sqrtf(a11 - L10 * L10);
                float L21 = (a12 - L20 * L10) / L11;
                float L31 = (a13 - L30 * L10) / L11;
                float L22 = sqrtf(a22 - L20 * L20 - L21 * L21);
                float L32 = (a23 - L30 * L20 - L31 * L21) / L22;
                float L33 = sqrtf(a33 - L30 * L30 - L31 * L31 - L32 * L32);
                // forward solve L y = G
                float y0 = g0 / L00;
                float y1 = (g1 - L10 * y0) / L11;
                float y2 = (g2 - L20 * y0 - L21 * y1) / L22;
                float y3 = (g3 - L30 * y0 - L31 * y1 - L32 * y2) / L33;
                // back solve L^T d = y
                float d3 = y3 / L33;
                float d2 = (y2 - L32 * d3) / L22;
                float d1 = (y1 - L21 * d2 - L31 * d3) / L11;
                float d0 = (y0 - L10 * d1 - L20 * d2 - L30 * d3) / L00;
                evalt[0] = theta[0] + d0;
                evalt[1] = theta[1] + d1;
                evalt[2] = theta[2] + d2;
                evalt[3] = theta[3] + d3;
            }
        }
    }

    if (j == NSTEPS) {
        __syncthreads();
        if (tid < 4)       out[batch * 4 + tid] = theta[tid];
        else if (tid == 4) out[B_ * 4 + batch]  = *costp;
    }
}

extern "C" void kernel_launch(void* const* d_in, const int* in_sizes, int n_in,
                              void* d_out, int out_size, void* d_ws, size_t ws_size,
                              hipStream_t stream) {
    const float* J      = (const float*)d_in[0];
    const float* bvec   = (const float*)d_in[1];
    const float* conf   = (const float*)d_in[2];
    const float* theta0 = (const float*)d_in[3];
    float* ws  = (float*)d_ws;
    float* out = (float*)d_out;

    hipLaunchKernelGGL(lm_init, dim3(1), dim3(128), 0, stream, ws, theta0);
    for (int j = 0; j <= NSTEPS; ++j) {
        hipLaunchKernelGGL(lm_pass, dim3(B_ * BPB), dim3(THREADS), 0, stream,
                           J, bvec, conf, ws);
        hipLaunchKernelGGL(lm_solve, dim3(B_), dim3(64), 0, stream, ws, out, j);
    }
}

// Round 4
// 1514.313 us; speedup vs baseline: 3.2900x; 3.2900x over previous
//
#include <hip/hip_runtime.h>
#include <math.h>

// ---------------------------------------------------------------------------
// Batched Levenberg-Marquardt, Huber IRLS, B=32, M=307200, N=4, 30 steps.
//
// Fusion: cost(theta_k) and H,G(theta_k) computed in ONE pass (the reference
// always accepts the step).  31 data passes total.
//
// R4: occupancy WITHOUT register forcing.  R3 proved 75% occupancy sustains
// 3.2 TB/s real HBM traffic, but __launch_bounds__(256,8) clamped VGPR to 32
// and spilled accumulators (300 MB/pass scratch writes).  Now: no min-waves
// clause (lean body compiles ~24-56 VGPR naturally), grid supplies occupancy:
// 60 blocks/batch = 1920 blocks = 7680 waves (94% of 8192 slots).
// UNROLL=2, OUTER=10: 60*256*2*10 == 307200 exactly, no tail.
//
// ws layout (floats):
//   [0,128)    theta (32x4) | [128,256) eval_theta | [256,288) lambda
//   [288,320)  cost  | [320,352) stop | [352, 352+32*60*16) partials
// ---------------------------------------------------------------------------

#define B_      32
#define M_      307200
#define NSTEPS  30
#define BPB     60                    // blocks per batch
#define THREADS 256
#define TPBATCH (BPB * THREADS)       // 15360 threads per batch
#define UNROLL  2
#define OUTER   10                    // OUTER*UNROLL*TPBATCH == M_

#define WS_THETA 0
#define WS_EVAL  128
#define WS_LAMB  256
#define WS_COST  288
#define WS_STOP  320
#define WS_PART  352

__global__ void lm_init(float* __restrict__ ws, const float* __restrict__ theta0) {
    int i = threadIdx.x;
    if (i < 128) {
        float t = theta0[i];
        ws[WS_THETA + i] = t;
        ws[WS_EVAL + i]  = t;
    }
    if (i < 32) {
        ws[WS_LAMB + i] = 0.1f;
        ws[WS_COST + i] = 0.0f;
        ((int*)(ws + WS_STOP))[i] = 0;
    }
}

__global__ __launch_bounds__(THREADS) void lm_pass(
        const float* __restrict__ J, const float* __restrict__ bvec,
        const float* __restrict__ conf, float* __restrict__ ws) {
    const int batch = blockIdx.x & 31;
    const int chunk = blockIdx.x >> 5;

    const int* stopf = (const int*)(ws + WS_STOP);
    if (stopf[batch]) return;   // frozen batch: results would be discarded

    const float* th = ws + WS_EVAL + batch * 4;
    const float t0 = th[0], t1 = th[1], t2 = th[2], t3 = th[3];

    const float4* __restrict__ Jb = (const float4*)(J + (size_t)batch * M_ * 4);
    const float*  __restrict__ bb = bvec + (size_t)batch * M_;
    const float*  __restrict__ cb = conf + (size_t)batch * M_;

    float c_acc = 0.f;
    float g0 = 0.f, g1 = 0.f, g2 = 0.f, g3 = 0.f;
    float h00 = 0.f, h01 = 0.f, h02 = 0.f, h03 = 0.f;
    float h11 = 0.f, h12 = 0.f, h13 = 0.f;
    float h22 = 0.f, h23 = 0.f, h33 = 0.f;

    const int m0 = chunk * THREADS + (int)threadIdx.x;    // [0, TPBATCH)

    for (int outer = 0; outer < OUTER; ++outer) {
        const int base = outer * (UNROLL * TPBATCH) + m0;
        float4 jv[UNROLL];
        float  bv[UNROLL];
        float  cf[UNROLL];
        #pragma unroll
        for (int k = 0; k < UNROLL; ++k) {
            const int m = base + k * TPBATCH;
            jv[k] = Jb[m];
            bv[k] = bb[m];
            cf[k] = cb[m];
        }
        #pragma unroll
        for (int k = 0; k < UNROLL; ++k) {
            float pred = jv[k].x * t0 + jv[k].y * t1 + jv[k].z * t2 + jv[k].w * t3;
            float r = bv[k] - pred;
            // scaled huber, a = 0.01 -> a^2 = 1e-4, x = r^2 / a^2
            float x  = r * r * 1.0e4f;
            float sx = sqrtf(x + 1e-8f);
            float isx = fmaxf(1.1920929e-7f, 1.0f / sx);
            bool small = (x <= 1.0f);
            float loss = small ? x : (2.0f * sx - 1.0f);
            float d1   = small ? 1.0f : isx;
            c_acc += loss * 1.0e-4f * cf[k];
            float w  = d1 * cf[k];
            float wr = w * r;
            g0 += wr * jv[k].x; g1 += wr * jv[k].y;
            g2 += wr * jv[k].z; g3 += wr * jv[k].w;
            float wx = w * jv[k].x, wy = w * jv[k].y, wz = w * jv[k].z;
            h00 += wx * jv[k].x; h01 += wx * jv[k].y;
            h02 += wx * jv[k].z; h03 += wx * jv[k].w;
            h11 += wy * jv[k].y; h12 += wy * jv[k].z; h13 += wy * jv[k].w;
            h22 += wz * jv[k].z; h23 += wz * jv[k].w;
            h33 += (w * jv[k].w) * jv[k].w;
        }
    }

    float acc[15] = {c_acc, g0, g1, g2, g3,
                     h00, h01, h02, h03, h11, h12, h13, h22, h23, h33};
    #pragma unroll
    for (int v = 0; v < 15; ++v) {
        float s = acc[v];
        #pragma unroll
        for (int off = 32; off > 0; off >>= 1)
            s += __shfl_down(s, off, 64);
        acc[v] = s;
    }

    __shared__ float red[4][15];
    const int lane = threadIdx.x & 63;
    const int wave = threadIdx.x >> 6;
    if (lane == 0) {
        #pragma unroll
        for (int v = 0; v < 15; ++v) red[wave][v] = acc[v];
    }
    __syncthreads();
    if (threadIdx.x < 15) {
        int v = threadIdx.x;
        float s = red[0][v] + red[1][v] + red[2][v] + red[3][v];
        ws[WS_PART + (batch * BPB + chunk) * 16 + v] = s;
    }
}

// Cross-block reduce + state update + damped 4x4 Cholesky solve.
__global__ __launch_bounds__(64) void lm_solve(
        float* __restrict__ ws, float* __restrict__ out, int j) {
    const int batch = blockIdx.x;
    const int tid = threadIdx.x;
    float* theta = ws + WS_THETA + batch * 4;
    float* evalt = ws + WS_EVAL + batch * 4;
    float* lambp = ws + WS_LAMB + batch;
    float* costp = ws + WS_COST + batch;
    int*   stopp = (int*)(ws + WS_STOP) + batch;
    const float* part = ws + WS_PART + batch * BPB * 16;

    __shared__ float vals[15];
    const bool stopped = (*stopp != 0);   // block-uniform

    if (!stopped) {
        if (tid < 15) {
            float s = 0.f;
            #pragma unroll 10
            for (int k = 0; k < BPB; ++k) s += part[k * 16 + tid];
            vals[tid] = s;
        }
        __syncthreads();
        if (tid == 0) {
            float new_cost = vals[0];
            float l = *lambp;
            bool stop_now = false;
            if (j == 0) {
                *costp = new_cost;           // cost0; theta/eval already theta0
            } else {
                float prev = *costp;
                float nl = l * (new_cost > prev ? 10.0f : 0.1f);
                nl = fminf(fmaxf(nl, 1e-6f), 100.0f);
                stop_now = fabsf(new_cost - prev) <= (1e-8f + 1e-8f * fabsf(prev));
                theta[0] = evalt[0]; theta[1] = evalt[1];
                theta[2] = evalt[2]; theta[3] = evalt[3];
                *costp = new_cost;
                *lambp = nl;
                l = nl;
                if (stop_now) *stopp = 1;
            }
            if (!stop_now && j < NSTEPS) {
                float g0 = vals[1], g1 = vals[2], g2 = vals[3], g3 = vals[4];
                float a00 = vals[5],  a01 = vals[6],  a02 = vals[7], a03 = vals[8];
                float a11 = vals[9],  a12 = vals[10], a13 = vals[11];
                float a22 = vals[12], a23 = vals[13], a33 = vals[14];
                // LM damping: H[i][i] += max(lambda * H[i][i], 1e-6)
                a00 += fmaxf(l * a00, 1e-6f);
                a11 += fmaxf(l * a11, 1e-6f);
                a22 += fmaxf(l * a22, 1e-6f);
                a33 += fmaxf(l * a33, 1e-6f);
                // Cholesky
                float L00 = sqrtf(a00);
                float L10 = a01 / L00, L20 = a02 / L00, L30 = a03 / L00;
                float L11 = sqrtf(a11 - L10 * L10);
                float L21 = (a12 - L20 * L10) / L11;
                float L31 = (a13 - L30 * L10) / L11;
                float L22 = sqrtf(a22 - L20 * L20 - L21 * L21);
                float L32 = (a23 - L30 * L20 - L31 * L21) / L22;
                float L33 = sqrtf(a33 - L30 * L30 - L31 * L31 - L32 * L32);
                // forward solve L y = G
                float y0 = g0 / L00;
                float y1 = (g1 - L10 * y0) / L11;
                float y2 = (g2 - L20 * y0 - L21 * y1) / L22;
                float y3 = (g3 - L30 * y0 - L31 * y1 - L32 * y2) / L33;
                // back solve L^T d = y
                float d3 = y3 / L33;
                float d2 = (y2 - L32 * d3) / L22;
                float d1 = (y1 - L21 * d2 - L31 * d3) / L11;
                float d0 = (y0 - L10 * d1 - L20 * d2 - L30 * d3) / L00;
                evalt[0] = theta[0] + d0;
                evalt[1] = theta[1] + d1;
                evalt[2] = theta[2] + d2;
                evalt[3] = theta[3] + d3;
            }
        }
    }

    if (j == NSTEPS) {
        __syncthreads();
        if (tid < 4)       out[batch * 4 + tid] = theta[tid];
        else if (tid == 4) out[B_ * 4 + batch]  = *costp;
    }
}

extern "C" void kernel_launch(void* const* d_in, const int* in_sizes, int n_in,
                              void* d_out, int out_size, void* d_ws, size_t ws_size,
                              hipStream_t stream) {
    const float* J      = (const float*)d_in[0];
    const float* bvec   = (const float*)d_in[1];
    const float* conf   = (const float*)d_in[2];
    const float* theta0 = (const float*)d_in[3];
    float* ws  = (float*)d_ws;
    float* out = (float*)d_out;

    hipLaunchKernelGGL(lm_init, dim3(1), dim3(128), 0, stream, ws, theta0);
    for (int j = 0; j <= NSTEPS; ++j) {
        hipLaunchKernelGGL(lm_pass, dim3(B_ * BPB), dim3(THREADS), 0, stream,
                           J, bvec, conf, ws);
        hipLaunchKernelGGL(lm_solve, dim3(B_), dim3(64), 0, stream, ws, out, j);
    }
}